// Round 9
// baseline (332.170 us; speedup 1.0000x reference)
//
#include <hip/hip_runtime.h>
#include <cmath>

// AttentionBlock: GroupNorm -> QKV 1x1 -> 8-head attention (L=1024) -> proj -> residual
// B=16, C=512, L=1024, 32 groups, 8 heads (ch=64). fp32 in/out, bf16 MFMA internally.

#define BATCH 16
#define CDIM 512
#define LDIM 1024
#define NX (8388608u)  // B*C*L
#define NQ (786432u)   // 1536*512
#define NP (262144u)   // 512*512

typedef unsigned short u16;
typedef u16 ushort8v __attribute__((ext_vector_type(8)));
typedef __bf16 bf16x8_t __attribute__((ext_vector_type(8)));
typedef float f32x4 __attribute__((ext_vector_type(4)));

__device__ __forceinline__ u16 f2bf(float f) {
  unsigned u = __float_as_uint(f);
  unsigned r = u + 0x7fffu + ((u >> 16) & 1u);  // RNE
  return (u16)(r >> 16);
}
__device__ __forceinline__ unsigned pack2(float a, float b) {
  return (unsigned)f2bf(a) | ((unsigned)f2bf(b) << 16);
}
// truncating bf16 pack: [hi16(a) | hi16(b)<<16] in one v_perm_b32
__device__ __forceinline__ unsigned pack2t(float a, float b) {
  return __builtin_amdgcn_perm(__float_as_uint(b), __float_as_uint(a), 0x07060302u);
}
// truncate to bf16 value (numerator-consistent denominator terms)
__device__ __forceinline__ float bftrunc(float x) {
  return __uint_as_float(__float_as_uint(x) & 0xffff0000u);
}
__device__ __forceinline__ float fast_exp2(float x) {
#if __has_builtin(__builtin_amdgcn_exp2f)
  return __builtin_amdgcn_exp2f(x);  // v_exp_f32 = 2^x
#else
  return exp2f(x);
#endif
}
__device__ __forceinline__ f32x4 mfma16(ushort8v a, ushort8v b, f32x4 c) {
  return __builtin_amdgcn_mfma_f32_16x16x32_bf16(
      __builtin_bit_cast(bf16x8_t, a), __builtin_bit_cast(bf16x8_t, b), c, 0, 0, 0);
}

// ---------------- GroupNorm stats: per-(b,c) scale/shift ----------------
__global__ __launch_bounds__(256) void gn_stats_kernel(const float* __restrict__ x,
                                                       const float* __restrict__ w,
                                                       const float* __restrict__ bvec,
                                                       float* __restrict__ scl,
                                                       float* __restrict__ sh) {
  int bg = blockIdx.x;
  int bb = bg >> 5, g = bg & 31;
  size_t base = ((size_t)bb * CDIM + g * 16) * LDIM;
  const float4* x4 = (const float4*)(x + base);
  int tid = threadIdx.x;
  float sum = 0.f, ss = 0.f;
#pragma unroll
  for (int i = 0; i < 16; ++i) {
    float4 v = x4[tid + 256 * i];
    sum += v.x + v.y + v.z + v.w;
    ss += v.x * v.x + v.y * v.y + v.z * v.z + v.w * v.w;
  }
#pragma unroll
  for (int off = 32; off; off >>= 1) {
    sum += __shfl_xor(sum, off);
    ss += __shfl_xor(ss, off);
  }
  __shared__ float rs[4], rq[4];
  int lane = tid & 63, wv = tid >> 6;
  if (lane == 0) { rs[wv] = sum; rq[wv] = ss; }
  __syncthreads();
  sum = rs[0] + rs[1] + rs[2] + rs[3];
  ss = rq[0] + rq[1] + rq[2] + rq[3];
  const float inv_n = 1.f / (16.f * 1024.f);
  float mean = sum * inv_n;
  float var = ss * inv_n - mean * mean;
  float rstd = rsqrtf(var + 1e-4f);
  if (tid < 16) {
    int c = g * 16 + tid;
    float s = w[c] * rstd;
    scl[bb * CDIM + c] = s;
    sh[bb * CDIM + c] = bvec[c] - mean * s;
  }
}

// ---------------- prep: GN-normalized x -> bf16 xn; pack weights -> bf16 ----------------
// Flat ranges: [0,NX) xn (GN applied), [NX,NX+NQ) qkv_w, [rest] proj_w.
// All range boundaries are multiples of 2048 -> per-block uniform branch.
__global__ __launch_bounds__(256) void prep_kernel(const float* __restrict__ x,
                                                   const float* __restrict__ scl,
                                                   const float* __restrict__ sh,
                                                   const float* __restrict__ wq,
                                                   const float* __restrict__ wp,
                                                   u16* __restrict__ xn,
                                                   u16* __restrict__ wqb,
                                                   u16* __restrict__ wpb) {
  size_t i = (size_t)blockIdx.x * 2048 + (size_t)threadIdx.x * 8;
  float s_ = 1.f, h_ = 0.f;
  const float* sp;
  u16* dp;
  size_t off;
  if (i < NX) {
    off = i;
    sp = x;
    dp = xn;
    size_t bc = i >> 10;  // b*CDIM + c (L=1024, 8-elem groups never straddle)
    s_ = scl[bc];
    h_ = sh[bc];
  } else if (i < NX + NQ) {
    off = i - NX;
    sp = wq;
    dp = wqb;
  } else {
    off = i - NX - NQ;
    sp = wp;
    dp = wpb;
  }
  float4 a = *(const float4*)&sp[off];
  float4 b = *(const float4*)&sp[off + 4];
  uint4 o;
  o.x = pack2(a.x * s_ + h_, a.y * s_ + h_);
  o.y = pack2(a.z * s_ + h_, a.w * s_ + h_);
  o.z = pack2(b.x * s_ + h_, b.y * s_ + h_);
  o.w = pack2(b.z * s_ + h_, b.w * s_ + h_);
  *(uint4*)&dp[off] = o;
}

// ---------------- MFMA GEMM, 128x128 tile, BK=32, all-bf16 inputs ----------------
// MODE 0: merged QKV (grid.y=12): m0<512 -> Q (transposed out qt[bh][t][c], scaled
//         by 0.125*log2e), <1024 -> K (transposed kt), else V -> v[b][c][l].
// MODE 2: proj -> fp32 out + bias + residual.
template <int MODE>
__global__ __launch_bounds__(256) void gemm_mfma(
    const u16* __restrict__ Wb, const float* __restrict__ biasg,
    const u16* __restrict__ Xb, const float* __restrict__ resid,
    u16* __restrict__ qo, u16* __restrict__ ko,
    u16* __restrict__ vo, float* __restrict__ fo) {
  __shared__ __align__(16) u16 Ws[128][40];  // [m][k], pad 40
  __shared__ __align__(16) u16 Xs[128][40];  // [n][k]
  int bb = blockIdx.z;
  int m0 = blockIdx.y * 128;
  int n0 = blockIdx.x * 128;
  int tid = threadIdx.x;
  int w = tid >> 6, lane = tid & 63, quad = lane >> 4, l15 = lane & 15;
  int wm = (w >> 1) * 64, wn = (w & 1) * 64;
  f32x4 acc[4][4] = {};  // QK path: [nsub][msub]; else: [msub][nsub]
  int xkb = tid >> 5, xnb = tid & 31;
  bool qkpath = (MODE == 0) && (m0 < 1024);

  for (int kk = 0; kk < 512; kk += 32) {
    // A: 128 m x 32 k bf16, 2 x ushort8 per thread (f = tid+256r: m=f>>2, kc=(f&3)*8)
    uint4 aw[2];
#pragma unroll
    for (int r = 0; r < 2; ++r) {
      int f = tid + 256 * r;
      aw[r] = *(const uint4*)&Wb[(size_t)(m0 + (f >> 2)) * 512 + kk + (f & 3) * 8];
    }
    // X: 32 c x 128 n bf16, transpose-pack 4x4 in registers
    ushort4 xu[4];
#pragma unroll
    for (int r = 0; r < 4; ++r)
      xu[r] = *(const ushort4*)&Xb[((size_t)bb * CDIM + kk + xkb * 4 + r) * LDIM + n0 + xnb * 4];
    uint2 xw[4];
#pragma unroll
    for (int j = 0; j < 4; ++j) {
      const u16* p0 = (const u16*)&xu[0];
      const u16* p1 = (const u16*)&xu[1];
      const u16* p2 = (const u16*)&xu[2];
      const u16* p3 = (const u16*)&xu[3];
      xw[j].x = (unsigned)p0[j] | ((unsigned)p1[j] << 16);
      xw[j].y = (unsigned)p2[j] | ((unsigned)p3[j] << 16);
    }
    __syncthreads();
#pragma unroll
    for (int r = 0; r < 2; ++r) {
      int f = tid + 256 * r;
      *(uint4*)&Ws[f >> 2][(f & 3) * 8] = aw[r];
    }
#pragma unroll
    for (int j = 0; j < 4; ++j) *(uint2*)&Xs[xnb * 4 + j][xkb * 4] = xw[j];
    __syncthreads();
    ushort8v af[4], bfr[4];
#pragma unroll
    for (int i = 0; i < 4; ++i) af[i] = *(const ushort8v*)&Ws[wm + i * 16 + l15][quad * 8];
#pragma unroll
    for (int i = 0; i < 4; ++i) bfr[i] = *(const ushort8v*)&Xs[wn + i * 16 + l15][quad * 8];
    if (qkpath) {
#pragma unroll
      for (int i = 0; i < 4; ++i)
#pragma unroll
        for (int j = 0; j < 4; ++j) acc[j][i] = mfma16(bfr[j], af[i], acc[j][i]);  // D[n][m]
    } else {
#pragma unroll
      for (int i = 0; i < 4; ++i)
#pragma unroll
        for (int j = 0; j < 4; ++j) acc[i][j] = mfma16(af[i], bfr[j], acc[i][j]);  // D[m][n]
    }
  }

  if (MODE == 0 && m0 < 1024) {
    bool isQ = (m0 < 512);
    // log2e folded into Q so attention can use raw v_exp_f32 (2^x)
    float qscale = isQ ? (0.125f * 1.44269504f) : 1.0f;
    u16* dst = isQ ? qo : ko;
    int cbase0 = m0 - (isQ ? 0 : 512) + wm;
#pragma unroll
    for (int i = 0; i < 4; ++i) {
      int cg = cbase0 + i * 16 + l15;
      float bv = biasg[m0 + wm + i * 16 + l15];
      int hh = cg >> 6, cl = cg & 63;
      size_t rowbase = ((size_t)(bb * 8 + hh) * 1024) * 64 + cl;
#pragma unroll
      for (int j = 0; j < 4; ++j)
#pragma unroll
        for (int r = 0; r < 4; ++r) {
          int t = n0 + wn + j * 16 + quad * 4 + r;
          dst[rowbase + (size_t)t * 64] = f2bf((acc[j][i][r] + bv) * qscale);
        }
    }
  } else if (MODE == 0) {
#pragma unroll
    for (int i = 0; i < 4; ++i)
#pragma unroll
      for (int r = 0; r < 4; ++r) {
        int m_abs = m0 + wm + i * 16 + quad * 4 + r;
        float bv = biasg[m_abs];
        int cg = m_abs - 1024;
#pragma unroll
        for (int j = 0; j < 4; ++j) {
          int n = n0 + wn + j * 16 + l15;
          vo[((size_t)bb * CDIM + cg) * LDIM + n] = f2bf(acc[i][j][r] + bv);
        }
      }
  } else {
#pragma unroll
    for (int i = 0; i < 4; ++i)
#pragma unroll
      for (int r = 0; r < 4; ++r) {
        int m_abs = m0 + wm + i * 16 + quad * 4 + r;
        float bv = biasg[m_abs];
#pragma unroll
        for (int j = 0; j < 4; ++j) {
          int n = n0 + wn + j * 16 + l15;
          size_t off = ((size_t)bb * CDIM + m_abs) * LDIM + n;
          fo[off] = acc[i][j][r] + bv + resid[off];
        }
      }
  }
}

// ---------------- Attention: no-max softmax, split-s 2-way, 8 blocks/CU ----------------
// Grid (128 bh, 16 tblk-of-64): linear id % 8 == bh % 8 -> head-local XCD (R7:
// FETCH 141->42 MB). Block: 4 waves = 2 t-groups x 2 s-halves -> 2048 blocks =
// 8 blocks/CU (LDS 19.5 KB, VGPR ~60 both fit) = 32 waves/CU: 2x the TLP of
// R5/R7/R8 which were pinned at 128.7 us by load-latency convoys the compiler
// wouldn't let us pipeline away (it re-serializes source-level prefetch; R8
// VGPR=60 proves the rotation was dropped). NO aggressive launch_bounds: R6's
// (256,8) forced VGPR 32 -> 1.9 GB spill traffic. (256,4) caps at 128 regs.
// Q pre-scaled by 0.125*log2e -> p = v_exp_f32(score). Denominator = per-lane
// sums of TRUNCATED p (numerator-consistent). Ps wave-private, no barriers in
// the loop; split-s partials merge exactly (no-max softmax) in 2 LDS rounds.
__global__ __launch_bounds__(256, 4) void attn_mfma(const u16* __restrict__ qt,
                                                    const u16* __restrict__ kt,
                                                    const u16* __restrict__ vv,
                                                    u16* __restrict__ av_out) {
  __shared__ __align__(16) u16 Ps[4][32][40];  // per-wave P tile [t][s], 10 KB
  __shared__ float Cb[2][64][18];              // wave-pair combine, 9 KB
  int bh = blockIdx.x;
  int t0b = blockIdx.y * 64;
  int b = bh >> 3, h = bh & 7;
  int tid = threadIdx.x;
  int w = tid >> 6, lane = tid & 63, quad = lane >> 4, l15 = lane & 15;
  int tg = w >> 1, shalf = w & 1;
  int t0w = t0b + tg * 32;
  int sbeg = shalf * 512;
  size_t head = (size_t)bh * 65536;  // 1024*64
  const u16* kbase = kt + head;
  const u16* vbase = vv + head;

  ushort8v qf[2][2];
#pragma unroll
  for (int ts = 0; ts < 2; ++ts)
#pragma unroll
    for (int kc = 0; kc < 2; ++kc)
      qf[ts][kc] =
          *(const ushort8v*)&qt[head + (size_t)(t0w + ts * 16 + l15) * 64 + kc * 32 + quad * 8];

  f32x4 Co[4][2] = {};
  float lacc[2] = {0.f, 0.f};

  // prefetch first K and V tiles of this wave's s-half
  ushort8v kf[2][2];
#pragma unroll
  for (int ms = 0; ms < 2; ++ms)
#pragma unroll
    for (int kc = 0; kc < 2; ++kc)
      kf[ms][kc] =
          *(const ushort8v*)&kbase[(size_t)(sbeg + ms * 16 + l15) * 64 + kc * 32 + quad * 8];
  ushort8v vf[4];
#pragma unroll
  for (int cs = 0; cs < 4; ++cs)
    vf[cs] = *(const ushort8v*)&vbase[(size_t)(cs * 16 + l15) * 1024 + sbeg + quad * 8];

  for (int si = 0; si < 512; si += 32) {
    int s0 = sbeg + si;
    int sn = sbeg + ((si + 32) & 511);  // wrap inside s-half; last reload unused
    // QK^T -> S^T tile (rows=s, cols=t)
    f32x4 st[2][2];
#pragma unroll
    for (int ts = 0; ts < 2; ++ts)
#pragma unroll
      for (int ms = 0; ms < 2; ++ms) {
        f32x4 z = {};
        z = mfma16(kf[ms][0], qf[ts][0], z);
        st[ts][ms] = mfma16(kf[ms][1], qf[ts][1], z);
      }
    // K prefetch next tile
#pragma unroll
    for (int ms = 0; ms < 2; ++ms)
#pragma unroll
      for (int kc = 0; kc < 2; ++kc)
        kf[ms][kc] =
            *(const ushort8v*)&kbase[(size_t)(sn + ms * 16 + l15) * 64 + kc * 32 + quad * 8];
    // exp2, truncate-consistent denominator, pack, wave-private LDS
#pragma unroll
    for (int ts = 0; ts < 2; ++ts) {
      float p0 = fast_exp2(st[ts][0].x), p1 = fast_exp2(st[ts][0].y);
      float p2 = fast_exp2(st[ts][0].z), p3 = fast_exp2(st[ts][0].w);
      float p4 = fast_exp2(st[ts][1].x), p5 = fast_exp2(st[ts][1].y);
      float p6 = fast_exp2(st[ts][1].z), p7 = fast_exp2(st[ts][1].w);
      lacc[ts] += ((bftrunc(p0) + bftrunc(p1)) + (bftrunc(p2) + bftrunc(p3))) +
                  ((bftrunc(p4) + bftrunc(p5)) + (bftrunc(p6) + bftrunc(p7)));
      uint2 u0, u1;
      u0.x = pack2t(p0, p1);
      u0.y = pack2t(p2, p3);
      u1.x = pack2t(p4, p5);
      u1.y = pack2t(p6, p7);
      *(uint2*)&Ps[w][ts * 16 + l15][quad * 4] = u0;
      *(uint2*)&Ps[w][ts * 16 + l15][16 + quad * 4] = u1;
    }
    // same-wave LDS RAW: ordered by lgkmcnt, no barrier needed
    ushort8v pb[2];
#pragma unroll
    for (int ts = 0; ts < 2; ++ts) pb[ts] = *(const ushort8v*)&Ps[w][ts * 16 + l15][quad * 8];
#pragma unroll
    for (int cs = 0; cs < 4; ++cs)
#pragma unroll
      for (int ts = 0; ts < 2; ++ts) Co[cs][ts] = mfma16(vf[cs], pb[ts], Co[cs][ts]);
    // V prefetch next tile
#pragma unroll
    for (int cs = 0; cs < 4; ++cs)
      vf[cs] = *(const ushort8v*)&vbase[(size_t)(cs * 16 + l15) * 1024 + sn + quad * 8];
  }

  // intra-wave denominator reduce over quads (lanes share l15=t)
#pragma unroll
  for (int ts = 0; ts < 2; ++ts) {
    lacc[ts] += __shfl_xor(lacc[ts], 16);
    lacc[ts] += __shfl_xor(lacc[ts], 32);
  }

  // wave-pair combine: shalf=1 partials -> shalf=0 (2 rounds through Cb)
  __syncthreads();
  if (shalf == 1) {
#pragma unroll
    for (int cs = 0; cs < 2; ++cs)
#pragma unroll
      for (int ts = 0; ts < 2; ++ts)
#pragma unroll
        for (int r = 0; r < 4; ++r) Cb[tg][lane][cs * 8 + ts * 4 + r] = Co[cs][ts][r];
    Cb[tg][lane][16] = lacc[0];
    Cb[tg][lane][17] = lacc[1];
  }
  __syncthreads();
  if (shalf == 0) {
#pragma unroll
    for (int cs = 0; cs < 2; ++cs)
#pragma unroll
      for (int ts = 0; ts < 2; ++ts)
#pragma unroll
        for (int r = 0; r < 4; ++r) Co[cs][ts][r] += Cb[tg][lane][cs * 8 + ts * 4 + r];
    lacc[0] += Cb[tg][lane][16];
    lacc[1] += Cb[tg][lane][17];
  }
  __syncthreads();
  if (shalf == 1) {
#pragma unroll
    for (int cs = 2; cs < 4; ++cs)
#pragma unroll
      for (int ts = 0; ts < 2; ++ts)
#pragma unroll
        for (int r = 0; r < 4; ++r) Cb[tg][lane][(cs - 2) * 8 + ts * 4 + r] = Co[cs][ts][r];
  }
  __syncthreads();
  if (shalf == 0) {
#pragma unroll
    for (int cs = 2; cs < 4; ++cs)
#pragma unroll
      for (int ts = 0; ts < 2; ++ts)
#pragma unroll
        for (int r = 0; r < 4; ++r) Co[cs][ts][r] += Cb[tg][lane][(cs - 2) * 8 + ts * 4 + r];
    float inv[2] = {1.f / lacc[0], 1.f / lacc[1]};
#pragma unroll
    for (int cs = 0; cs < 4; ++cs)
#pragma unroll
      for (int ts = 0; ts < 2; ++ts) {
        int t = t0w + ts * 16 + l15;
#pragma unroll
        for (int r = 0; r < 4; ++r) {
          int c = h * 64 + cs * 16 + quad * 4 + r;
          av_out[((size_t)b * CDIM + c) * LDIM + t] = f2bf(Co[cs][ts][r] * inv[ts]);
        }
      }
  }
}

extern "C" void kernel_launch(void* const* d_in, const int* in_sizes, int n_in,
                              void* d_out, int out_size, void* d_ws, size_t ws_size,
                              hipStream_t stream) {
  const float* x = (const float*)d_in[0];
  const float* norm_w = (const float*)d_in[1];
  const float* norm_b = (const float*)d_in[2];
  const float* qkv_w = (const float*)d_in[3];
  const float* qkv_b = (const float*)d_in[4];
  const float* proj_w = (const float*)d_in[5];
  const float* proj_b = (const float*)d_in[6];
  float* out = (float*)d_out;

  const size_t NE = (size_t)BATCH * CDIM * LDIM;  // 8.39M
  float* scl = (float*)d_ws;
  float* sh = scl + BATCH * CDIM;
  u16* qt = (u16*)(sh + BATCH * CDIM);  // [bh][t][c] bf16
  u16* kt = qt + NE;                    // [bh][s][c] bf16
  u16* vv = kt + NE;                    // [b][c][l]  bf16
  u16* av = vv + NE;                    // [b][c][l]  bf16
  u16* xn = av + NE;                    // [b][c][l]  bf16 (GN applied)
  u16* wqb = xn + NE;                   // [1536][512] bf16
  u16* wpb = wqb + NQ;                  // [512][512]  bf16

  gn_stats_kernel<<<dim3(BATCH * 32), dim3(256), 0, stream>>>(x, norm_w, norm_b, scl, sh);
  prep_kernel<<<dim3((NX + NQ + NP) / 2048), dim3(256), 0, stream>>>(
      x, scl, sh, qkv_w, proj_w, xn, wqb, wpb);
  gemm_mfma<0><<<dim3(8, 12, BATCH), dim3(256), 0, stream>>>(
      wqb, qkv_b, xn, (const float*)nullptr, qt, kt, vv, (float*)nullptr);
  attn_mfma<<<dim3(128, 16), dim3(256), 0, stream>>>(qt, kt, vv, av);
  gemm_mfma<2><<<dim3(8, 4, BATCH), dim3(256), 0, stream>>>(
      wpb, proj_b, av, x, (u16*)nullptr, (u16*)nullptr, (u16*)nullptr, out);
}

// Round 10
// 256.925 us; speedup vs baseline: 1.2929x; 1.2929x over previous
//
#include <hip/hip_runtime.h>
#include <cmath>

// AttentionBlock: GroupNorm -> QKV 1x1 -> 8-head attention (L=1024) -> proj -> residual
// B=16, C=512, L=1024, 32 groups, 8 heads (ch=64). fp32 in/out, bf16 MFMA internally.

#define BATCH 16
#define CDIM 512
#define LDIM 1024
#define NX (8388608u)  // B*C*L
#define NQ (786432u)   // 1536*512
#define NP (262144u)   // 512*512

typedef unsigned short u16;
typedef u16 ushort8v __attribute__((ext_vector_type(8)));
typedef __bf16 bf16x8_t __attribute__((ext_vector_type(8)));
typedef float f32x4 __attribute__((ext_vector_type(4)));

__device__ __forceinline__ u16 f2bf(float f) {
  unsigned u = __float_as_uint(f);
  unsigned r = u + 0x7fffu + ((u >> 16) & 1u);  // RNE
  return (u16)(r >> 16);
}
__device__ __forceinline__ unsigned pack2(float a, float b) {
  return (unsigned)f2bf(a) | ((unsigned)f2bf(b) << 16);
}
// truncating bf16 pack: [hi16(a) | hi16(b)<<16] in one v_perm_b32
__device__ __forceinline__ unsigned pack2t(float a, float b) {
  return __builtin_amdgcn_perm(__float_as_uint(b), __float_as_uint(a), 0x07060302u);
}
// truncate to bf16 value (numerator-consistent denominator terms)
__device__ __forceinline__ float bftrunc(float x) {
  return __uint_as_float(__float_as_uint(x) & 0xffff0000u);
}
__device__ __forceinline__ float fast_exp2(float x) {
#if __has_builtin(__builtin_amdgcn_exp2f)
  return __builtin_amdgcn_exp2f(x);  // v_exp_f32 = 2^x
#else
  return exp2f(x);
#endif
}
__device__ __forceinline__ f32x4 mfma16(ushort8v a, ushort8v b, f32x4 c) {
  return __builtin_amdgcn_mfma_f32_16x16x32_bf16(
      __builtin_bit_cast(bf16x8_t, a), __builtin_bit_cast(bf16x8_t, b), c, 0, 0, 0);
}

// ---------------- GroupNorm stats: per-(b,c) scale/shift ----------------
__global__ __launch_bounds__(256) void gn_stats_kernel(const float* __restrict__ x,
                                                       const float* __restrict__ w,
                                                       const float* __restrict__ bvec,
                                                       float* __restrict__ scl,
                                                       float* __restrict__ sh) {
  int bg = blockIdx.x;
  int bb = bg >> 5, g = bg & 31;
  size_t base = ((size_t)bb * CDIM + g * 16) * LDIM;
  const float4* x4 = (const float4*)(x + base);
  int tid = threadIdx.x;
  float sum = 0.f, ss = 0.f;
#pragma unroll
  for (int i = 0; i < 16; ++i) {
    float4 v = x4[tid + 256 * i];
    sum += v.x + v.y + v.z + v.w;
    ss += v.x * v.x + v.y * v.y + v.z * v.z + v.w * v.w;
  }
#pragma unroll
  for (int off = 32; off; off >>= 1) {
    sum += __shfl_xor(sum, off);
    ss += __shfl_xor(ss, off);
  }
  __shared__ float rs[4], rq[4];
  int lane = tid & 63, wv = tid >> 6;
  if (lane == 0) { rs[wv] = sum; rq[wv] = ss; }
  __syncthreads();
  sum = rs[0] + rs[1] + rs[2] + rs[3];
  ss = rq[0] + rq[1] + rq[2] + rq[3];
  const float inv_n = 1.f / (16.f * 1024.f);
  float mean = sum * inv_n;
  float var = ss * inv_n - mean * mean;
  float rstd = rsqrtf(var + 1e-4f);
  if (tid < 16) {
    int c = g * 16 + tid;
    float s = w[c] * rstd;
    scl[bb * CDIM + c] = s;
    sh[bb * CDIM + c] = bvec[c] - mean * s;
  }
}

// ---------------- prep: GN-normalized x -> bf16 xn; pack weights -> bf16 ----------------
__global__ __launch_bounds__(256) void prep_kernel(const float* __restrict__ x,
                                                   const float* __restrict__ scl,
                                                   const float* __restrict__ sh,
                                                   const float* __restrict__ wq,
                                                   const float* __restrict__ wp,
                                                   u16* __restrict__ xn,
                                                   u16* __restrict__ wqb,
                                                   u16* __restrict__ wpb) {
  size_t i = (size_t)blockIdx.x * 2048 + (size_t)threadIdx.x * 8;
  float s_ = 1.f, h_ = 0.f;
  const float* sp;
  u16* dp;
  size_t off;
  if (i < NX) {
    off = i;
    sp = x;
    dp = xn;
    size_t bc = i >> 10;  // b*CDIM + c
    s_ = scl[bc];
    h_ = sh[bc];
  } else if (i < NX + NQ) {
    off = i - NX;
    sp = wq;
    dp = wqb;
  } else {
    off = i - NX - NQ;
    sp = wp;
    dp = wpb;
  }
  float4 a = *(const float4*)&sp[off];
  float4 b = *(const float4*)&sp[off + 4];
  uint4 o;
  o.x = pack2(a.x * s_ + h_, a.y * s_ + h_);
  o.y = pack2(a.z * s_ + h_, a.w * s_ + h_);
  o.z = pack2(b.x * s_ + h_, b.y * s_ + h_);
  o.w = pack2(b.z * s_ + h_, b.w * s_ + h_);
  *(uint4*)&dp[off] = o;
}

// ---------------- MFMA GEMM, 128x128 tile, BK=32, all-bf16 inputs ----------------
// MODE 0: merged QKV (grid.y=12): m0<512 -> Q (transposed out qt[bh][t][c], scaled
//         by 0.125*log2e), <1024 -> K (transposed kt), else V -> v[b][c][l].
// MODE 2: proj -> fp32 out + bias + residual.
template <int MODE>
__global__ __launch_bounds__(256) void gemm_mfma(
    const u16* __restrict__ Wb, const float* __restrict__ biasg,
    const u16* __restrict__ Xb, const float* __restrict__ resid,
    u16* __restrict__ qo, u16* __restrict__ ko,
    u16* __restrict__ vo, float* __restrict__ fo) {
  __shared__ __align__(16) u16 Ws[128][40];  // [m][k], pad 40
  __shared__ __align__(16) u16 Xs[128][40];  // [n][k]
  int bb = blockIdx.z;
  int m0 = blockIdx.y * 128;
  int n0 = blockIdx.x * 128;
  int tid = threadIdx.x;
  int w = tid >> 6, lane = tid & 63, quad = lane >> 4, l15 = lane & 15;
  int wm = (w >> 1) * 64, wn = (w & 1) * 64;
  f32x4 acc[4][4] = {};  // QK path: [nsub][msub]; else: [msub][nsub]
  int xkb = tid >> 5, xnb = tid & 31;
  bool qkpath = (MODE == 0) && (m0 < 1024);

  for (int kk = 0; kk < 512; kk += 32) {
    uint4 aw[2];
#pragma unroll
    for (int r = 0; r < 2; ++r) {
      int f = tid + 256 * r;
      aw[r] = *(const uint4*)&Wb[(size_t)(m0 + (f >> 2)) * 512 + kk + (f & 3) * 8];
    }
    ushort4 xu[4];
#pragma unroll
    for (int r = 0; r < 4; ++r)
      xu[r] = *(const ushort4*)&Xb[((size_t)bb * CDIM + kk + xkb * 4 + r) * LDIM + n0 + xnb * 4];
    uint2 xw[4];
#pragma unroll
    for (int j = 0; j < 4; ++j) {
      const u16* p0 = (const u16*)&xu[0];
      const u16* p1 = (const u16*)&xu[1];
      const u16* p2 = (const u16*)&xu[2];
      const u16* p3 = (const u16*)&xu[3];
      xw[j].x = (unsigned)p0[j] | ((unsigned)p1[j] << 16);
      xw[j].y = (unsigned)p2[j] | ((unsigned)p3[j] << 16);
    }
    __syncthreads();
#pragma unroll
    for (int r = 0; r < 2; ++r) {
      int f = tid + 256 * r;
      *(uint4*)&Ws[f >> 2][(f & 3) * 8] = aw[r];
    }
#pragma unroll
    for (int j = 0; j < 4; ++j) *(uint2*)&Xs[xnb * 4 + j][xkb * 4] = xw[j];
    __syncthreads();
    ushort8v af[4], bfr[4];
#pragma unroll
    for (int i = 0; i < 4; ++i) af[i] = *(const ushort8v*)&Ws[wm + i * 16 + l15][quad * 8];
#pragma unroll
    for (int i = 0; i < 4; ++i) bfr[i] = *(const ushort8v*)&Xs[wn + i * 16 + l15][quad * 8];
    if (qkpath) {
#pragma unroll
      for (int i = 0; i < 4; ++i)
#pragma unroll
        for (int j = 0; j < 4; ++j) acc[j][i] = mfma16(bfr[j], af[i], acc[j][i]);  // D[n][m]
    } else {
#pragma unroll
      for (int i = 0; i < 4; ++i)
#pragma unroll
        for (int j = 0; j < 4; ++j) acc[i][j] = mfma16(af[i], bfr[j], acc[i][j]);  // D[m][n]
    }
  }

  if (MODE == 0 && m0 < 1024) {
    bool isQ = (m0 < 512);
    float qscale = isQ ? (0.125f * 1.44269504f) : 1.0f;
    u16* dst = isQ ? qo : ko;
    int cbase0 = m0 - (isQ ? 0 : 512) + wm;
#pragma unroll
    for (int i = 0; i < 4; ++i) {
      int cg = cbase0 + i * 16 + l15;
      float bv = biasg[m0 + wm + i * 16 + l15];
      int hh = cg >> 6, cl = cg & 63;
      size_t rowbase = ((size_t)(bb * 8 + hh) * 1024) * 64 + cl;
#pragma unroll
      for (int j = 0; j < 4; ++j)
#pragma unroll
        for (int r = 0; r < 4; ++r) {
          int t = n0 + wn + j * 16 + quad * 4 + r;
          dst[rowbase + (size_t)t * 64] = f2bf((acc[j][i][r] + bv) * qscale);
        }
    }
  } else if (MODE == 0) {
#pragma unroll
    for (int i = 0; i < 4; ++i)
#pragma unroll
      for (int r = 0; r < 4; ++r) {
        int m_abs = m0 + wm + i * 16 + quad * 4 + r;
        float bv = biasg[m_abs];
        int cg = m_abs - 1024;
#pragma unroll
        for (int j = 0; j < 4; ++j) {
          int n = n0 + wn + j * 16 + l15;
          vo[((size_t)bb * CDIM + cg) * LDIM + n] = f2bf(acc[i][j][r] + bv);
        }
      }
  } else {
#pragma unroll
    for (int i = 0; i < 4; ++i)
#pragma unroll
      for (int r = 0; r < 4; ++r) {
        int m_abs = m0 + wm + i * 16 + quad * 4 + r;
        float bv = biasg[m_abs];
#pragma unroll
        for (int j = 0; j < 4; ++j) {
          int n = n0 + wn + j * 16 + l15;
          size_t off = ((size_t)bb * CDIM + m_abs) * LDIM + n;
          fo[off] = acc[i][j][r] + bv + resid[off];
        }
      }
  }
}

// ---------------- Attention: cooperative LDS-staged K/V, double-buffered (m97 anatomy) ----
// Grid (128 bh, 8 tblk): linear id % 8 == bh % 8 -> head-local XCD (FETCH = compulsory).
// Block: 4 waves x 32 t = 128 t, one bh, full s-scan in 32-s chunks.
// R5/R7/R8/R9 all pinned at ~130 us, MfmaUtil 10%: per-wave VMEM convoys -- all 4
// waves loaded IDENTICAL K/V fragments from global (4x redundant), compiler
// serializes load->MFMA per tile and re-schedules away in-wave prefetch.
// Fix = the GEMM ladder's answer: block stages K(32s x 64c) and V(64c x 32s) into
// padded LDS once per chunk (1 global b128 + 1 ds_write per thread each), double
// buffered, one barrier per chunk. Next chunk's global loads issue at top of
// compute, waited only at the pre-barrier ds_write -> full compute phase covers
// L2 latency. Fragments come from LDS (fine-grained lgkmcnt, 2-way-free padding).
// Q pre-scaled by 0.125*log2e -> p = v_exp_f32(score); denominator = per-lane sums
// of TRUNCATED p (numerator-consistent); Ps wave-private.
__global__ __launch_bounds__(256) void attn_mfma(const u16* __restrict__ qt,
                                                 const u16* __restrict__ kt,
                                                 const u16* __restrict__ vv,
                                                 u16* __restrict__ av_out) {
  __shared__ __align__(16) u16 Ks[2][32][72];  // [buf][s][c], pad 72: 9.2 KB
  __shared__ __align__(16) u16 Vs[2][64][40];  // [buf][c][s], pad 40: 10.2 KB
  __shared__ __align__(16) u16 Ps[4][32][40];  // per-wave P [t][s]:   10.2 KB
  int bh = blockIdx.x;
  int t0b = blockIdx.y * 128;
  int b = bh >> 3, h = bh & 7;
  int tid = threadIdx.x;
  int w = tid >> 6, lane = tid & 63, quad = lane >> 4, l15 = lane & 15;
  int t0w = t0b + w * 32;
  size_t head = (size_t)bh * 65536;  // 1024*64
  const u16* kbase = kt + head;
  const u16* vbase = vv + head;

  // staging indices
  int sK = tid >> 3, cK8 = (tid & 7) * 8;  // K: thread -> (s row, 8c seg); coalesced 4KB
  int cV = tid >> 2, sV8 = (tid & 3) * 8;  // V: thread -> (c row, 8s seg)

  ushort8v qf[2][2];
#pragma unroll
  for (int ts = 0; ts < 2; ++ts)
#pragma unroll
    for (int kc = 0; kc < 2; ++kc)
      qf[ts][kc] =
          *(const ushort8v*)&qt[head + (size_t)(t0w + ts * 16 + l15) * 64 + kc * 32 + quad * 8];

  f32x4 Co[4][2] = {};
  float lacc[2] = {0.f, 0.f};

  // stage chunk 0 into buffer 0
  {
    uint4 k0 = *(const uint4*)&kbase[(size_t)tid * 8];
    uint4 v0 = *(const uint4*)&vbase[(size_t)cV * 1024 + sV8];
    *(uint4*)&Ks[0][sK][cK8] = k0;
    *(uint4*)&Vs[0][cV][sV8] = v0;
  }
  __syncthreads();

  int cur = 0;
  for (int ci = 0; ci < 32; ++ci) {
    int sn = ((ci + 1) & 31) * 32;  // next chunk start (wraps; final write unused)
    // issue next chunk's global loads now; waited at the ds_write below
    uint4 kn = *(const uint4*)&kbase[(size_t)sn * 64 + tid * 8];
    uint4 vn = *(const uint4*)&vbase[(size_t)cV * 1024 + sn + sV8];

    // ---- compute on buf[cur] ----
    ushort8v kf[2][2];
#pragma unroll
    for (int ms = 0; ms < 2; ++ms)
#pragma unroll
      for (int kc = 0; kc < 2; ++kc)
        kf[ms][kc] = *(const ushort8v*)&Ks[cur][ms * 16 + l15][kc * 32 + quad * 8];
    ushort8v vf[4];
#pragma unroll
    for (int cs = 0; cs < 4; ++cs) vf[cs] = *(const ushort8v*)&Vs[cur][cs * 16 + l15][quad * 8];

    f32x4 st[2][2];
#pragma unroll
    for (int ts = 0; ts < 2; ++ts)
#pragma unroll
      for (int ms = 0; ms < 2; ++ms) {
        f32x4 z = {};
        z = mfma16(kf[ms][0], qf[ts][0], z);
        st[ts][ms] = mfma16(kf[ms][1], qf[ts][1], z);
      }
#pragma unroll
    for (int ts = 0; ts < 2; ++ts) {
      float p0 = fast_exp2(st[ts][0].x), p1 = fast_exp2(st[ts][0].y);
      float p2 = fast_exp2(st[ts][0].z), p3 = fast_exp2(st[ts][0].w);
      float p4 = fast_exp2(st[ts][1].x), p5 = fast_exp2(st[ts][1].y);
      float p6 = fast_exp2(st[ts][1].z), p7 = fast_exp2(st[ts][1].w);
      lacc[ts] += ((bftrunc(p0) + bftrunc(p1)) + (bftrunc(p2) + bftrunc(p3))) +
                  ((bftrunc(p4) + bftrunc(p5)) + (bftrunc(p6) + bftrunc(p7)));
      uint2 u0, u1;
      u0.x = pack2t(p0, p1);
      u0.y = pack2t(p2, p3);
      u1.x = pack2t(p4, p5);
      u1.y = pack2t(p6, p7);
      *(uint2*)&Ps[w][ts * 16 + l15][quad * 4] = u0;
      *(uint2*)&Ps[w][ts * 16 + l15][16 + quad * 4] = u1;
    }
    ushort8v pb[2];
#pragma unroll
    for (int ts = 0; ts < 2; ++ts) pb[ts] = *(const ushort8v*)&Ps[w][ts * 16 + l15][quad * 8];
#pragma unroll
    for (int cs = 0; cs < 4; ++cs)
#pragma unroll
      for (int ts = 0; ts < 2; ++ts) Co[cs][ts] = mfma16(vf[cs], pb[ts], Co[cs][ts]);

    // ---- write next chunk into the other buffer, then barrier ----
    int nxt = cur ^ 1;
    *(uint4*)&Ks[nxt][sK][cK8] = kn;
    *(uint4*)&Vs[nxt][cV][sV8] = vn;
    __syncthreads();
    cur = nxt;
  }

  // denominator: sum over quads (lanes share l15=t)
#pragma unroll
  for (int ts = 0; ts < 2; ++ts) {
    lacc[ts] += __shfl_xor(lacc[ts], 16);
    lacc[ts] += __shfl_xor(lacc[ts], 32);
  }
  float inv[2] = {1.f / lacc[0], 1.f / lacc[1]};
#pragma unroll
  for (int cs = 0; cs < 4; ++cs)
#pragma unroll
    for (int ts = 0; ts < 2; ++ts) {
      int t = t0w + ts * 16 + l15;
#pragma unroll
      for (int r = 0; r < 4; ++r) {
        int c = h * 64 + cs * 16 + quad * 4 + r;
        av_out[((size_t)b * CDIM + c) * LDIM + t] = f2bf(Co[cs][ts][r] * inv[ts]);
      }
    }
}

extern "C" void kernel_launch(void* const* d_in, const int* in_sizes, int n_in,
                              void* d_out, int out_size, void* d_ws, size_t ws_size,
                              hipStream_t stream) {
  const float* x = (const float*)d_in[0];
  const float* norm_w = (const float*)d_in[1];
  const float* norm_b = (const float*)d_in[2];
  const float* qkv_w = (const float*)d_in[3];
  const float* qkv_b = (const float*)d_in[4];
  const float* proj_w = (const float*)d_in[5];
  const float* proj_b = (const float*)d_in[6];
  float* out = (float*)d_out;

  const size_t NE = (size_t)BATCH * CDIM * LDIM;  // 8.39M
  float* scl = (float*)d_ws;
  float* sh = scl + BATCH * CDIM;
  u16* qt = (u16*)(sh + BATCH * CDIM);  // [bh][t][c] bf16
  u16* kt = qt + NE;                    // [bh][s][c] bf16
  u16* vv = kt + NE;                    // [b][c][l]  bf16
  u16* av = vv + NE;                    // [b][c][l]  bf16
  u16* xn = av + NE;                    // [b][c][l]  bf16 (GN applied)
  u16* wqb = xn + NE;                   // [1536][512] bf16
  u16* wpb = wqb + NQ;                  // [512][512]  bf16

  gn_stats_kernel<<<dim3(BATCH * 32), dim3(256), 0, stream>>>(x, norm_w, norm_b, scl, sh);
  prep_kernel<<<dim3((NX + NQ + NP) / 2048), dim3(256), 0, stream>>>(
      x, scl, sh, qkv_w, proj_w, xn, wqb, wpb);
  gemm_mfma<0><<<dim3(8, 12, BATCH), dim3(256), 0, stream>>>(
      wqb, qkv_b, xn, (const float*)nullptr, qt, kt, vv, (float*)nullptr);
  attn_mfma<<<dim3(128, 8), dim3(256), 0, stream>>>(qt, kt, vv, av);
  gemm_mfma<2><<<dim3(8, 4, BATCH), dim3(256), 0, stream>>>(
      wpb, proj_b, av, x, (u16*)nullptr, (u16*)nullptr, (u16*)nullptr, out);
}

// Round 11
// 213.907 us; speedup vs baseline: 1.5529x; 1.2011x over previous
//
#include <hip/hip_runtime.h>
#include <cmath>

// AttentionBlock: GroupNorm -> QKV 1x1 -> 8-head attention (L=1024) -> proj -> residual
// B=16, C=512, L=1024, 32 groups, 8 heads (ch=64). fp32 in/out, bf16 MFMA internally.

#define BATCH 16
#define CDIM 512
#define LDIM 1024
#define NQ (786432u)  // 1536*512
#define NP (262144u)  // 512*512

#define AS1 __attribute__((address_space(1)))
#define AS3 __attribute__((address_space(3)))

typedef unsigned short u16;
typedef u16 ushort8v __attribute__((ext_vector_type(8)));
typedef __bf16 bf16x8_t __attribute__((ext_vector_type(8)));
typedef float f32x4 __attribute__((ext_vector_type(4)));

__device__ __forceinline__ u16 f2bf(float f) {
  unsigned u = __float_as_uint(f);
  unsigned r = u + 0x7fffu + ((u >> 16) & 1u);  // RNE
  return (u16)(r >> 16);
}
__device__ __forceinline__ unsigned pack2(float a, float b) {
  return (unsigned)f2bf(a) | ((unsigned)f2bf(b) << 16);
}
// truncating bf16 pack: [hi16(a) | hi16(b)<<16] in one v_perm_b32
__device__ __forceinline__ unsigned pack2t(float a, float b) {
  return __builtin_amdgcn_perm(__float_as_uint(b), __float_as_uint(a), 0x07060302u);
}
// truncate to bf16 value (numerator-consistent denominator terms)
__device__ __forceinline__ float bftrunc(float x) {
  return __uint_as_float(__float_as_uint(x) & 0xffff0000u);
}
__device__ __forceinline__ float fast_exp2(float x) {
#if __has_builtin(__builtin_amdgcn_exp2f)
  return __builtin_amdgcn_exp2f(x);  // v_exp_f32 = 2^x
#else
  return exp2f(x);
#endif
}
__device__ __forceinline__ f32x4 mfma16(ushort8v a, ushort8v b, f32x4 c) {
  return __builtin_amdgcn_mfma_f32_16x16x32_bf16(
      __builtin_bit_cast(bf16x8_t, a), __builtin_bit_cast(bf16x8_t, b), c, 0, 0, 0);
}
// async global->LDS, 16B/lane: LDS dst = wave-uniform base + lane*16
__device__ __forceinline__ void g2l16(const u16* g, u16* l) {
  __builtin_amdgcn_global_load_lds((const AS1 void*)g, (AS3 void*)l, 16, 0, 0);
}

// ---------------- GroupNorm stats: per-(b,c) scale/shift ----------------
__global__ __launch_bounds__(256) void gn_stats_kernel(const float* __restrict__ x,
                                                       const float* __restrict__ w,
                                                       const float* __restrict__ bvec,
                                                       float* __restrict__ scl,
                                                       float* __restrict__ sh) {
  int bg = blockIdx.x;
  int bb = bg >> 5, g = bg & 31;
  size_t base = ((size_t)bb * CDIM + g * 16) * LDIM;
  const float4* x4 = (const float4*)(x + base);
  int tid = threadIdx.x;
  float sum = 0.f, ss = 0.f;
#pragma unroll
  for (int i = 0; i < 16; ++i) {
    float4 v = x4[tid + 256 * i];
    sum += v.x + v.y + v.z + v.w;
    ss += v.x * v.x + v.y * v.y + v.z * v.z + v.w * v.w;
  }
#pragma unroll
  for (int off = 32; off; off >>= 1) {
    sum += __shfl_xor(sum, off);
    ss += __shfl_xor(ss, off);
  }
  __shared__ float rs[4], rq[4];
  int lane = tid & 63, wv = tid >> 6;
  if (lane == 0) { rs[wv] = sum; rq[wv] = ss; }
  __syncthreads();
  sum = rs[0] + rs[1] + rs[2] + rs[3];
  ss = rq[0] + rq[1] + rq[2] + rq[3];
  const float inv_n = 1.f / (16.f * 1024.f);
  float mean = sum * inv_n;
  float var = ss * inv_n - mean * mean;
  float rstd = rsqrtf(var + 1e-4f);
  if (tid < 16) {
    int c = g * 16 + tid;
    float s = w[c] * rstd;
    scl[bb * CDIM + c] = s;
    sh[bb * CDIM + c] = bvec[c] - mean * s;
  }
}

// ---------------- weight pack: fp32 -> bf16 flat ----------------
__global__ __launch_bounds__(256) void wpack_kernel(const float* __restrict__ wq,
                                                    const float* __restrict__ wp,
                                                    u16* __restrict__ wqb,
                                                    u16* __restrict__ wpb) {
  size_t i = (size_t)blockIdx.x * 2048 + (size_t)threadIdx.x * 8;
  const float* sp;
  u16* dp;
  size_t off;
  if (i < NQ) {
    off = i;
    sp = wq;
    dp = wqb;
  } else {
    off = i - NQ;
    sp = wp;
    dp = wpb;
  }
  float4 a = *(const float4*)&sp[off];
  float4 b = *(const float4*)&sp[off + 4];
  uint4 o;
  o.x = pack2(a.x, a.y);
  o.y = pack2(a.z, a.w);
  o.z = pack2(b.x, b.y);
  o.w = pack2(b.z, b.w);
  *(uint4*)&dp[off] = o;
}

// ---------------- xpose: x[b][c][l] fp32 -> GN -> xnT[b][l][c] bf16 ----------------
// 64x64 tiles via LDS. Grid (16 ltiles, 8 ctiles, 16 b), 256 threads.
__global__ __launch_bounds__(256) void xpose_kernel(const float* __restrict__ x,
                                                    const float* __restrict__ scl,
                                                    const float* __restrict__ sh,
                                                    u16* __restrict__ xnT) {
  __shared__ u16 T[64][72];  // [l][c], pad 72 (144B rows, 16B-aligned)
  int b = blockIdx.z, c0 = blockIdx.y * 64, l0 = blockIdx.x * 64;
  int tid = threadIdx.x;
  int ci = tid >> 4, ljs = (tid & 15) * 4;
#pragma unroll
  for (int rep = 0; rep < 4; ++rep) {
    int c = rep * 16 + ci;
    float s_ = scl[b * CDIM + c0 + c];
    float h_ = sh[b * CDIM + c0 + c];
    float4 v = *(const float4*)&x[((size_t)b * CDIM + c0 + c) * LDIM + l0 + ljs];
    T[ljs + 0][c] = f2bf(v.x * s_ + h_);
    T[ljs + 1][c] = f2bf(v.y * s_ + h_);
    T[ljs + 2][c] = f2bf(v.z * s_ + h_);
    T[ljs + 3][c] = f2bf(v.w * s_ + h_);
  }
  __syncthreads();
  int lr = tid >> 2, cs8 = (tid & 3) * 16;
  uint4 o0 = *(const uint4*)&T[lr][cs8];
  uint4 o1 = *(const uint4*)&T[lr][cs8 + 8];
  size_t dst = ((size_t)b * LDIM + l0 + lr) * CDIM + c0 + cs8;
  *(uint4*)&xnT[dst] = o0;
  *(uint4*)&xnT[dst + 8] = o1;
}

// ---------------- MFMA GEMM, m97 anatomy: global_load_lds staging ----------------
// Both operands [out][k] bf16 row-major, K=512, BK=32, 128x128 tile, 2 barriers/iter.
// MODE 0: merged QKV (grid.y=12): m0<512 -> Q (transposed out qt[bh][t][c], scaled
//         by 0.125*log2e), <1024 -> K (transposed kt), else V -> v[b][c][l].
// MODE 1: proj -> fp32 out + bias + residual. X = avT [b][l][c].
template <int MODE>
__global__ __launch_bounds__(256) void gemm_mfma(
    const u16* __restrict__ Wb, const float* __restrict__ biasg,
    const u16* __restrict__ Xt, const float* __restrict__ resid,
    u16* __restrict__ qo, u16* __restrict__ ko,
    u16* __restrict__ vo, float* __restrict__ fo) {
  __shared__ __align__(16) u16 As_[128][32];  // [m][k] - unpadded (global_load_lds)
  __shared__ __align__(16) u16 Xs_[128][32];  // [n][k]
  int bb = blockIdx.z;
  int m0 = blockIdx.y * 128;
  int n0 = blockIdx.x * 128;
  int tid = threadIdx.x;
  int w = tid >> 6, lane = tid & 63, quad = lane >> 4, l15 = lane & 15;
  int wm = (w >> 1) * 64, wn = (w & 1) * 64;
  int srow = lane >> 2, scol = (lane & 3) * 8;  // lane -> (row-in-16-slab, 8k seg)
  const u16* Xb = Xt + (size_t)bb * LDIM * CDIM;  // [n][k=512]
  f32x4 acc[4][4] = {};  // QK path: [nsub][msub]; else: [msub][nsub]
  bool qkpath = (MODE == 0) && (m0 < 1024);

  for (int kk = 0; kk < 512; kk += 32) {
    // async staging: wave w fills rows [w*32, w*32+32) of both tiles, 16B/lane
#pragma unroll
    for (int r = 0; r < 2; ++r) {
      int row = w * 32 + r * 16;
      g2l16(&Wb[(size_t)(m0 + row + srow) * 512 + kk + scol], &As_[row][0]);
      g2l16(&Xb[(size_t)(n0 + row + srow) * 512 + kk + scol], &Xs_[row][0]);
    }
    __syncthreads();  // drains vmcnt -> tiles visible
    ushort8v af[4], bfr[4];
#pragma unroll
    for (int i = 0; i < 4; ++i) af[i] = *(const ushort8v*)&As_[wm + i * 16 + l15][quad * 8];
#pragma unroll
    for (int i = 0; i < 4; ++i) bfr[i] = *(const ushort8v*)&Xs_[wn + i * 16 + l15][quad * 8];
    if (qkpath) {
#pragma unroll
      for (int i = 0; i < 4; ++i)
#pragma unroll
        for (int j = 0; j < 4; ++j) acc[j][i] = mfma16(bfr[j], af[i], acc[j][i]);  // D[n][m]
    } else {
#pragma unroll
      for (int i = 0; i < 4; ++i)
#pragma unroll
        for (int j = 0; j < 4; ++j) acc[i][j] = mfma16(af[i], bfr[j], acc[i][j]);  // D[m][n]
    }
    __syncthreads();  // protect tiles until all waves done reading
  }

  if (MODE == 0 && m0 < 1024) {
    bool isQ = (m0 < 512);
    float qscale = isQ ? (0.125f * 1.44269504f) : 1.0f;  // log2e folded into Q
    u16* dst = isQ ? qo : ko;
    int cbase0 = m0 - (isQ ? 0 : 512) + wm;
#pragma unroll
    for (int i = 0; i < 4; ++i) {
      int cg = cbase0 + i * 16 + l15;
      float bv = biasg[m0 + wm + i * 16 + l15];
      int hh = cg >> 6, cl = cg & 63;
      size_t rowbase = ((size_t)(bb * 8 + hh) * 1024) * 64 + cl;
#pragma unroll
      for (int j = 0; j < 4; ++j)
#pragma unroll
        for (int r = 0; r < 4; ++r) {
          int t = n0 + wn + j * 16 + quad * 4 + r;
          dst[rowbase + (size_t)t * 64] = f2bf((acc[j][i][r] + bv) * qscale);
        }
    }
  } else if (MODE == 0) {
#pragma unroll
    for (int i = 0; i < 4; ++i)
#pragma unroll
      for (int r = 0; r < 4; ++r) {
        int m_abs = m0 + wm + i * 16 + quad * 4 + r;
        float bv = biasg[m_abs];
        int cg = m_abs - 1024;
#pragma unroll
        for (int j = 0; j < 4; ++j) {
          int n = n0 + wn + j * 16 + l15;
          vo[((size_t)bb * CDIM + cg) * LDIM + n] = f2bf(acc[i][j][r] + bv);
        }
      }
  } else {
#pragma unroll
    for (int i = 0; i < 4; ++i)
#pragma unroll
      for (int r = 0; r < 4; ++r) {
        int m_abs = m0 + wm + i * 16 + quad * 4 + r;
        float bv = biasg[m_abs];
#pragma unroll
        for (int j = 0; j < 4; ++j) {
          int n = n0 + wn + j * 16 + l15;
          size_t off = ((size_t)bb * CDIM + m_abs) * LDIM + n;
          fo[off] = acc[i][j][r] + bv + resid[off];
        }
      }
  }
}

// ---------------- Attention: cooperative LDS-staged K/V, double-buffered ----------------
// Grid (128 bh, 8 tblk): linear id % 8 == bh % 8 -> head-local XCD. Block: 4 waves x 32 t.
// R10 WIN structure unchanged; only PV now computes O^T (operand swap) so the output
// lands as avT[b][l][c] -- proj's m97 GEMM wants [n][k], and stores get MORE coalesced.
// Denominator inv values broadcast across quads via tiny LDS table.
__global__ __launch_bounds__(256) void attn_mfma(const u16* __restrict__ qt,
                                                 const u16* __restrict__ kt,
                                                 const u16* __restrict__ vv,
                                                 u16* __restrict__ avT) {
  __shared__ __align__(16) u16 Ks[2][32][72];  // [buf][s][c], pad 72
  __shared__ __align__(16) u16 Vs[2][64][40];  // [buf][c][s], pad 40
  __shared__ __align__(16) u16 Ps[4][32][40];  // per-wave P [t][s]
  __shared__ float linv[4][32];                // per-wave inv-denominator by local t
  int bh = blockIdx.x;
  int t0b = blockIdx.y * 128;
  int b = bh >> 3, h = bh & 7;
  int tid = threadIdx.x;
  int w = tid >> 6, lane = tid & 63, quad = lane >> 4, l15 = lane & 15;
  int t0w = t0b + w * 32;
  size_t head = (size_t)bh * 65536;  // 1024*64
  const u16* kbase = kt + head;
  const u16* vbase = vv + head;

  int sK = tid >> 3, cK8 = (tid & 7) * 8;  // K staging: (s row, 8c seg)
  int cV = tid >> 2, sV8 = (tid & 3) * 8;  // V staging: (c row, 8s seg)

  ushort8v qf[2][2];
#pragma unroll
  for (int ts = 0; ts < 2; ++ts)
#pragma unroll
    for (int kc = 0; kc < 2; ++kc)
      qf[ts][kc] =
          *(const ushort8v*)&qt[head + (size_t)(t0w + ts * 16 + l15) * 64 + kc * 32 + quad * 8];

  f32x4 Co[2][4] = {};  // [tsub][csub]: rows = t, cols = c (O^T)
  float lacc[2] = {0.f, 0.f};

  {
    uint4 k0 = *(const uint4*)&kbase[(size_t)tid * 8];
    uint4 v0 = *(const uint4*)&vbase[(size_t)cV * 1024 + sV8];
    *(uint4*)&Ks[0][sK][cK8] = k0;
    *(uint4*)&Vs[0][cV][sV8] = v0;
  }
  __syncthreads();

  int cur = 0;
  for (int ci = 0; ci < 32; ++ci) {
    int sn = ((ci + 1) & 31) * 32;
    uint4 kn = *(const uint4*)&kbase[(size_t)sn * 64 + tid * 8];
    uint4 vn = *(const uint4*)&vbase[(size_t)cV * 1024 + sn + sV8];

    ushort8v kf[2][2];
#pragma unroll
    for (int ms = 0; ms < 2; ++ms)
#pragma unroll
      for (int kc = 0; kc < 2; ++kc)
        kf[ms][kc] = *(const ushort8v*)&Ks[cur][ms * 16 + l15][kc * 32 + quad * 8];
    ushort8v vf[4];
#pragma unroll
    for (int cs = 0; cs < 4; ++cs) vf[cs] = *(const ushort8v*)&Vs[cur][cs * 16 + l15][quad * 8];

    f32x4 st[2][2];
#pragma unroll
    for (int ts = 0; ts < 2; ++ts)
#pragma unroll
      for (int ms = 0; ms < 2; ++ms) {
        f32x4 z = {};
        z = mfma16(kf[ms][0], qf[ts][0], z);
        st[ts][ms] = mfma16(kf[ms][1], qf[ts][1], z);
      }
#pragma unroll
    for (int ts = 0; ts < 2; ++ts) {
      float p0 = fast_exp2(st[ts][0].x), p1 = fast_exp2(st[ts][0].y);
      float p2 = fast_exp2(st[ts][0].z), p3 = fast_exp2(st[ts][0].w);
      float p4 = fast_exp2(st[ts][1].x), p5 = fast_exp2(st[ts][1].y);
      float p6 = fast_exp2(st[ts][1].z), p7 = fast_exp2(st[ts][1].w);
      lacc[ts] += ((bftrunc(p0) + bftrunc(p1)) + (bftrunc(p2) + bftrunc(p3))) +
                  ((bftrunc(p4) + bftrunc(p5)) + (bftrunc(p6) + bftrunc(p7)));
      uint2 u0, u1;
      u0.x = pack2t(p0, p1);
      u0.y = pack2t(p2, p3);
      u1.x = pack2t(p4, p5);
      u1.y = pack2t(p6, p7);
      *(uint2*)&Ps[w][ts * 16 + l15][quad * 4] = u0;
      *(uint2*)&Ps[w][ts * 16 + l15][16 + quad * 4] = u1;
    }
    ushort8v pb[2];
#pragma unroll
    for (int ts = 0; ts < 2; ++ts) pb[ts] = *(const ushort8v*)&Ps[w][ts * 16 + l15][quad * 8];
    // PV with P as the A operand: D = P^T-row layout -> rows = t, cols = c (O^T)
#pragma unroll
    for (int ts = 0; ts < 2; ++ts)
#pragma unroll
      for (int cs = 0; cs < 4; ++cs) Co[ts][cs] = mfma16(pb[ts], vf[cs], Co[ts][cs]);

    int nxt = cur ^ 1;
    *(uint4*)&Ks[nxt][sK][cK8] = kn;
    *(uint4*)&Vs[nxt][cV][sV8] = vn;
    __syncthreads();
    cur = nxt;
  }

  // denominator: reduce over quads, broadcast by local t through LDS
#pragma unroll
  for (int ts = 0; ts < 2; ++ts) {
    lacc[ts] += __shfl_xor(lacc[ts], 16);
    lacc[ts] += __shfl_xor(lacc[ts], 32);
    if (quad == 0) linv[w][ts * 16 + l15] = 1.f / lacc[ts];
  }
  // same-wave LDS RAW: ordered by lgkmcnt
#pragma unroll
  for (int ts = 0; ts < 2; ++ts)
#pragma unroll
    for (int r = 0; r < 4; ++r) {
      int tl = ts * 16 + quad * 4 + r;
      float iv = linv[w][tl];
      size_t rowb = ((size_t)b * LDIM + t0w + tl) * CDIM + h * 64;
#pragma unroll
      for (int cs = 0; cs < 4; ++cs)
        avT[rowb + cs * 16 + l15] = f2bf(Co[ts][cs][r] * iv);
    }
}

extern "C" void kernel_launch(void* const* d_in, const int* in_sizes, int n_in,
                              void* d_out, int out_size, void* d_ws, size_t ws_size,
                              hipStream_t stream) {
  const float* x = (const float*)d_in[0];
  const float* norm_w = (const float*)d_in[1];
  const float* norm_b = (const float*)d_in[2];
  const float* qkv_w = (const float*)d_in[3];
  const float* qkv_b = (const float*)d_in[4];
  const float* proj_w = (const float*)d_in[5];
  const float* proj_b = (const float*)d_in[6];
  float* out = (float*)d_out;

  const size_t NE = (size_t)BATCH * CDIM * LDIM;  // 8.39M
  float* scl = (float*)d_ws;
  float* sh = scl + BATCH * CDIM;
  u16* qt = (u16*)(sh + BATCH * CDIM);  // [bh][t][c] bf16
  u16* kt = qt + NE;                    // [bh][s][c] bf16
  u16* vv = kt + NE;                    // [b][c][l]  bf16
  u16* av = vv + NE;                    // [b][l][c]  bf16 (O^T)
  u16* xn = av + NE;                    // [b][l][c]  bf16 (GN applied, transposed)
  u16* wqb = xn + NE;                   // [1536][512] bf16
  u16* wpb = wqb + NQ;                  // [512][512]  bf16

  gn_stats_kernel<<<dim3(BATCH * 32), dim3(256), 0, stream>>>(x, norm_w, norm_b, scl, sh);
  wpack_kernel<<<dim3((NQ + NP) / 2048), dim3(256), 0, stream>>>(qkv_w, proj_w, wqb, wpb);
  xpose_kernel<<<dim3(16, 8, BATCH), dim3(256), 0, stream>>>(x, scl, sh, xn);
  gemm_mfma<0><<<dim3(8, 12, BATCH), dim3(256), 0, stream>>>(
      wqb, qkv_b, xn, (const float*)nullptr, qt, kt, vv, (float*)nullptr);
  attn_mfma<<<dim3(128, 8), dim3(256), 0, stream>>>(qt, kt, vv, av);
  gemm_mfma<1><<<dim3(8, 4, BATCH), dim3(256), 0, stream>>>(
      wpb, proj_b, av, x, (u16*)nullptr, (u16*)nullptr, (u16*)nullptr, out);
}